// Round 8
// baseline (303.478 us; speedup 1.0000x reference)
//
#include <hip/hip_runtime.h>

// GCNConv forward: out = segment_sum(vals * (x@W)[cols], rows) + bias
// Round 15: sort_gather gather loop rewritten for 2x records-in-flight.
//  - half-wave pairing: lane<32 = record A, lane>=32 = record B; each lane
//    loads uint2 (4 features); one global load now carries TWO records.
//  - 8-slot masked batches = 16 records in flight/wave (was ~7 effective);
//    clamped-address + val=0 masking removes the MLP-1 tail loop.
//  - per-row acc = float4/half-wave; one shfl_xor(32) merge, float4 store.
//  r14 lesson: FETCH unchanged when removing L2-absorbed re-reads; the
//  h-gather latency-MLP product is the real wall.
//
// ws: h[N*128] bf16 | wt[128*264] bf16 | cursors[(NB<<4)+16] int |
//     bcv[NB*CAP] int2 | ovf[OVFCAP] int4

typedef __attribute__((ext_vector_type(8))) short short8;
typedef __attribute__((ext_vector_type(4))) float floatx4;
typedef __attribute__((ext_vector_type(2))) int intv2;

#define WT_K 264
#define GM_NODES 128
#define BSHIFT 6              // 64 rows per bucket
#define BROWS 64
#define CAP 1280              // records per bucket region; mean 1024, +8 sigma
#define NBMAX 1600            // max buckets (n_nodes <= 102400)
#define EPB 6400              // edges per fill block (25 per thread)
#define CSH 4                 // cursors padded to 16 ints = one 64B line
#define OVFCAP 65536

static __device__ __forceinline__ uint f2bf(float x) {  // RNE f32->bf16 bits
  uint u = __float_as_uint(x);
  return (u + 0x7fffu + ((u >> 16) & 1u)) >> 16;
}

union u4s8 { uint4 u; short8 s; };

// ---- W[k][f] f32 -> wt[f][k] bf16 (k padded to WT_K); also zero cursors ----
__global__ __launch_bounds__(256) void conv_w(const float* __restrict__ w,
                                              ushort* __restrict__ wt,
                                              int* __restrict__ cursors,
                                              int n_ints) {
  const int f = blockIdx.x;
  const int k = threadIdx.x;
  wt[f * WT_K + k] = (ushort)f2bf(w[k * 128 + f]);
  for (int i = blockIdx.x * 256 + threadIdx.x; i < n_ints; i += 128 * 256)
    cursors[i] = 0;
}

// ---- GEMM: h^T = W^T x^T via 16x16x32 bf16 MFMA; barrier-free k-loop ----
__global__ __launch_bounds__(256) void gemm_mfma(const float* __restrict__ x,
                                                 const ushort* __restrict__ wt,
                                                 ushort* __restrict__ h,
                                                 int n_nodes) {
  __shared__ ushort lw[128 * WT_K];    // 67.6 KB (only LDS use)
  const int t = threadIdx.x;
  const int lane = t & 63;
  const int wq = t >> 6;
  const int quad = lane >> 4;
  const int l15 = lane & 15;
  const int row0 = blockIdx.x * GM_NODES;

  {
    const uint4* src = (const uint4*)wt;
    uint4* dst = (uint4*)lw;
    for (int i = t; i < (128 * WT_K * 2) / 16; i += 256) dst[i] = src[i];
  }

  floatx4 acc[2][8];
#pragma unroll
  for (int nt = 0; nt < 2; ++nt)
#pragma unroll
    for (int mt = 0; mt < 8; ++mt) acc[nt][mt] = (floatx4){0.f, 0.f, 0.f, 0.f};

  // this wave's B-operand nodes: frag0 = n0, frag1 = n0+16 (fixed per lane)
  const int n0 = row0 + wq * 32 + l15;
  const int n1 = n0 + 16;
  const bool v0 = (n0 < n_nodes), v1 = (n1 < n_nodes);
  const float* p0 = x + (size_t)(v0 ? n0 : 0) * 256 + quad * 8;
  const float* p1 = x + (size_t)(v1 ? n1 : 0) * 256 + quad * 8;
  const float4 z4 = make_float4(0.f, 0.f, 0.f, 0.f);

  float4 cur0a = v0 ? *(const float4*)(p0 + 0) : z4;
  float4 cur0b = v0 ? *(const float4*)(p0 + 4) : z4;
  float4 cur1a = v1 ? *(const float4*)(p1 + 0) : z4;
  float4 cur1b = v1 ? *(const float4*)(p1 + 4) : z4;

  __syncthreads();   // W staged

  for (int kc = 0; kc < 8; ++kc) {
    float4 nxt0a, nxt0b, nxt1a, nxt1b;
    if (kc < 7) {
      const int o = (kc + 1) * 32;
      nxt0a = v0 ? *(const float4*)(p0 + o + 0) : z4;
      nxt0b = v0 ? *(const float4*)(p0 + o + 4) : z4;
      nxt1a = v1 ? *(const float4*)(p1 + o + 0) : z4;
      nxt1b = v1 ? *(const float4*)(p1 + o + 4) : z4;
    }

    u4s8 bf0, bf1;
    bf0.u.x = f2bf(cur0a.x) | (f2bf(cur0a.y) << 16);
    bf0.u.y = f2bf(cur0a.z) | (f2bf(cur0a.w) << 16);
    bf0.u.z = f2bf(cur0b.x) | (f2bf(cur0b.y) << 16);
    bf0.u.w = f2bf(cur0b.z) | (f2bf(cur0b.w) << 16);
    bf1.u.x = f2bf(cur1a.x) | (f2bf(cur1a.y) << 16);
    bf1.u.y = f2bf(cur1a.z) | (f2bf(cur1a.w) << 16);
    bf1.u.z = f2bf(cur1b.x) | (f2bf(cur1b.y) << 16);
    bf1.u.w = f2bf(cur1b.z) | (f2bf(cur1b.w) << 16);

#pragma unroll
    for (int mt = 0; mt < 8; ++mt) {
      const short8 afr =
          *(const short8*)&lw[(mt * 16 + l15) * WT_K + kc * 32 + quad * 8];
      acc[0][mt] = __builtin_amdgcn_mfma_f32_16x16x32_bf16(afr, bf0.s,
                                                           acc[0][mt], 0, 0, 0);
      acc[1][mt] = __builtin_amdgcn_mfma_f32_16x16x32_bf16(afr, bf1.s,
                                                           acc[1][mt], 0, 0, 0);
    }
    cur0a = nxt0a; cur0b = nxt0b; cur1a = nxt1a; cur1b = nxt1b;
  }

#pragma unroll
  for (int nt = 0; nt < 2; ++nt) {
    const int node = row0 + wq * 32 + nt * 16 + l15;
    if (node < n_nodes) {
#pragma unroll
      for (int mt = 0; mt < 8; ++mt) {
        uint2 p;
        p.x = f2bf(acc[nt][mt][0]) | (f2bf(acc[nt][mt][1]) << 16);
        p.y = f2bf(acc[nt][mt][2]) | (f2bf(acc[nt][mt][3]) << 16);
        *(uint2*)&h[(size_t)node * 128 + mt * 16 + quad * 4] = p;
      }
    }
  }
}

// ---- block-aggregated binning: 6400 edges/block, 1 atomic/(block,bucket) ----
__global__ __launch_bounds__(256) void fill_bin(
    const int* __restrict__ erows, const int* __restrict__ ecols,
    const float* __restrict__ evals, int* __restrict__ cursors,
    int2* __restrict__ bcv, int* __restrict__ ovf_cnt,
    int4* __restrict__ ovf, int n_edges, int nb) {
  __shared__ int2 rec[EPB];          // 51.2 KB packed records
  __shared__ short bkt[EPB];         // 12.8 KB bucket ids
  __shared__ int cnt[NBMAX], bas[NBMAX], cur[NBMAX];   // 19.2 KB
  const int t = threadIdx.x;
  const int e0 = blockIdx.x * EPB;
  const int n = min(EPB, n_edges - e0);
  if (n <= 0) return;

  for (int b = t; b < nb; b += 256) { cnt[b] = 0; cur[b] = 0; }
  __syncthreads();

  // load + pack + LDS histogram (coalesced NT sweep, 4-batched for MLP)
  {
    int i = t;
    for (; i + 768 < n; i += 1024) {
      int r0 = __builtin_nontemporal_load(&erows[e0 + i]);
      int r1 = __builtin_nontemporal_load(&erows[e0 + i + 256]);
      int r2 = __builtin_nontemporal_load(&erows[e0 + i + 512]);
      int r3 = __builtin_nontemporal_load(&erows[e0 + i + 768]);
      int c0 = __builtin_nontemporal_load(&ecols[e0 + i]);
      int c1 = __builtin_nontemporal_load(&ecols[e0 + i + 256]);
      int c2 = __builtin_nontemporal_load(&ecols[e0 + i + 512]);
      int c3 = __builtin_nontemporal_load(&ecols[e0 + i + 768]);
      float v0 = __builtin_nontemporal_load(&evals[e0 + i]);
      float v1 = __builtin_nontemporal_load(&evals[e0 + i + 256]);
      float v2 = __builtin_nontemporal_load(&evals[e0 + i + 512]);
      float v3 = __builtin_nontemporal_load(&evals[e0 + i + 768]);
      int2 p0; p0.x = c0 | ((r0 & (BROWS - 1)) << 17); p0.y = __float_as_int(v0);
      int2 p1; p1.x = c1 | ((r1 & (BROWS - 1)) << 17); p1.y = __float_as_int(v1);
      int2 p2; p2.x = c2 | ((r2 & (BROWS - 1)) << 17); p2.y = __float_as_int(v2);
      int2 p3; p3.x = c3 | ((r3 & (BROWS - 1)) << 17); p3.y = __float_as_int(v3);
      rec[i] = p0; rec[i + 256] = p1; rec[i + 512] = p2; rec[i + 768] = p3;
      const int b0 = r0 >> BSHIFT, b1 = r1 >> BSHIFT;
      const int b2 = r2 >> BSHIFT, b3 = r3 >> BSHIFT;
      bkt[i] = (short)b0; bkt[i + 256] = (short)b1;
      bkt[i + 512] = (short)b2; bkt[i + 768] = (short)b3;
      atomicAdd(&cnt[b0], 1); atomicAdd(&cnt[b1], 1);
      atomicAdd(&cnt[b2], 1); atomicAdd(&cnt[b3], 1);
    }
    for (; i < n; i += 256) {
      const int r = __builtin_nontemporal_load(&erows[e0 + i]);
      const int c = __builtin_nontemporal_load(&ecols[e0 + i]);
      const float v = __builtin_nontemporal_load(&evals[e0 + i]);
      int2 p; p.x = c | ((r & (BROWS - 1)) << 17); p.y = __float_as_int(v);
      rec[i] = p;
      const int b = r >> BSHIFT;
      bkt[i] = (short)b;
      atomicAdd(&cnt[b], 1);
    }
  }
  __syncthreads();

  // reserve global runs: one atomic per non-empty (block,bucket); 256-wide
  for (int b = t; b < nb; b += 256) {
    const int c = cnt[b];
    if (c > 0) bas[b] = atomicAdd(&cursors[b << CSH], c);
  }
  __syncthreads();

  // flush: contiguous 8B-record runs per bucket
  for (int i = t; i < n; i += 256) {
    const int b = (int)bkt[i];
    const int loc = atomicAdd(&cur[b], 1);
    const int pos = bas[b] + loc;
    const int2 p = rec[i];
    if (pos < CAP) {
      bcv[(size_t)b * CAP + pos] = p;
    } else {
      int op = atomicAdd(ovf_cnt, 1);
      if (op < OVFCAP) {
        int4 q;
        q.x = (b << BSHIFT) | ((p.x >> 17) & (BROWS - 1));   // row
        q.y = p.x & 0x1FFFF;                                 // col
        q.z = p.y; q.w = 0;
        ovf[op] = q;
      }
    }
  }
}

// ---- fused per-bucket counting sort (regs->LDS) + half-wave-paired gather ----
__global__ __launch_bounds__(256) void sort_gather(
    const ushort* __restrict__ h, const int* __restrict__ cursors,
    const int2* __restrict__ bcv, const float* __restrict__ bias,
    float* __restrict__ out, int n_nodes, int nb) {
  __shared__ int2 buf[CAP];            // 10.24 KB sorted records
  __shared__ int cnt[BROWS], start[BROWS], cur[BROWS];
  const int b = blockIdx.x;
  const int t = threadIdx.x;
  const int nrec = min(cursors[b << CSH], CAP);
  if (t < BROWS) cnt[t] = 0;
  __syncthreads();

  const int2* src = &bcv[(size_t)b * CAP];
  int2 r[5];
#pragma unroll
  for (int j = 0; j < 5; ++j) {
    const int i = t + j * 256;
    if (i < nrec) {
      intv2 rv = __builtin_nontemporal_load((const intv2*)&src[i]);
      r[j].x = rv[0]; r[j].y = rv[1];
    } else {
      r[j].x = 0; r[j].y = 0;
    }
  }
#pragma unroll
  for (int j = 0; j < 5; ++j) {
    const int i = t + j * 256;
    if (i < nrec) atomicAdd(&cnt[((uint)r[j].x) >> 17], 1);
  }
  __syncthreads();

  if (t < BROWS) {   // wave 0: 64-lane inclusive scan -> exclusive starts
    int c = cnt[t];
    int s = c;
#pragma unroll
    for (int off = 1; off < 64; off <<= 1) {
      int u = __shfl_up(s, off, 64);
      if (t >= off) s += u;
    }
    start[t] = s - c;
    cur[t] = s - c;
  }
  __syncthreads();

  // scatter into row-sorted LDS buffer (from regs; no second global pass)
#pragma unroll
  for (int j = 0; j < 5; ++j) {
    const int i = t + j * 256;
    if (i < nrec) {
      int pos = atomicAdd(&cur[((uint)r[j].x) >> 17], 1);
      buf[pos] = r[j];
    }
  }
  __syncthreads();

  // gather: wave w rows w*16..w*16+15. Half-wave pairing: lane<32 = even
  // record, lane>=32 = odd record; each lane loads uint2 (4 features) so one
  // load carries 2 records. 8 masked slots = 16 records in flight, no tail.
  const int lane = t & 63;
  const int w = t >> 6;
  const int half = lane >> 5;
  const int l5 = lane & 31;
  float4 bv4 = make_float4(0.f, 0.f, 0.f, 0.f);
  if (half == 0) bv4 = ((const float4*)bias)[l5];
  for (int rr = w * 16; rr < w * 16 + 16; ++rr) {
    const int node = b * BROWS + rr;
    if (node >= n_nodes) break;
    float4 acc = bv4;
    const int p = start[rr];
    const int k = cnt[rr];
    const int last = p + k - 1;      // k==0: loop never runs
    for (int q = 0; q < k; q += 16) {
      int2 e[8];
#pragma unroll
      for (int s = 0; s < 8; ++s) {
        const int raw = p + q + 2 * s + half;
        e[s] = buf[raw <= last ? raw : last];
        if (raw > last) e[s].y = 0;              // mask val -> contributes 0
      }
      uint2 u[8];
#pragma unroll
      for (int s = 0; s < 8; ++s)
        u[s] = *(const uint2*)(h + (size_t)((uint)e[s].x & 0x1FFFF) * 128 +
                               l5 * 4);
#pragma unroll
      for (int s = 0; s < 8; ++s) {
        const float v = __int_as_float(e[s].y);
        acc.x += v * __uint_as_float(u[s].x << 16);
        acc.y += v * __uint_as_float(u[s].x & 0xffff0000u);
        acc.z += v * __uint_as_float(u[s].y << 16);
        acc.w += v * __uint_as_float(u[s].y & 0xffff0000u);
      }
    }
    acc.x += __shfl_xor(acc.x, 32);
    acc.y += __shfl_xor(acc.y, 32);
    acc.z += __shfl_xor(acc.z, 32);
    acc.w += __shfl_xor(acc.w, 32);
    if (half == 0) ((float4*)(out + (size_t)node * 128))[l5] = acc;
  }
}

// ---- drain overflow spill list (expected near-empty; fixed grid for graph) ----
__global__ __launch_bounds__(256) void ovf_scatter(
    const ushort* __restrict__ h, const int* __restrict__ ovf_cnt,
    const int4* __restrict__ ovf, float* __restrict__ out) {
  const int n = min(*ovf_cnt, OVFCAP);
  const int lane = threadIdx.x & 63;
  const int wid = (blockIdx.x * 256 + threadIdx.x) >> 6;
  const int nw = gridDim.x * 4;
  for (int e = wid; e < n; e += nw) {
    int4 recq = ovf[e];
    float v = __int_as_float(recq.z);
    uint u = ((const uint*)(h + (size_t)recq.y * 128))[lane];
    float* op = out + (size_t)recq.x * 128 + lane * 2;
    atomicAdd(op, v * __uint_as_float(u << 16));
    atomicAdd(op + 1, v * __uint_as_float(u & 0xffff0000u));
  }
}

// ---- fallback (small ws): bias init + atomic scatter on bf16 h ----
__global__ __launch_bounds__(256) void init_bias(float* __restrict__ out,
                                                 const float* __restrict__ bias,
                                                 int n4) {
  int i = blockIdx.x * 256 + threadIdx.x;
  if (i < n4) {
    float4 b = ((const float4*)bias)[i & 31];
    ((float4*)out)[i] = b;
  }
}

__global__ __launch_bounds__(256) void scatter_edges(
    const ushort* __restrict__ h, const int* __restrict__ erows,
    const int* __restrict__ ecols, const float* __restrict__ evals,
    float* __restrict__ out, int n_edges) {
  int e = blockIdx.x * 4 + (threadIdx.x >> 6);
  if (e >= n_edges) return;
  int lane = threadIdx.x & 63;
  int row = erows[e];
  int col = ecols[e];
  float v = evals[e];
  uint u = ((const uint*)(h + (size_t)col * 128))[lane];
  float* op = out + (size_t)row * 128 + lane * 2;
  atomicAdd(op, v * __uint_as_float(u << 16));
  atomicAdd(op + 1, v * __uint_as_float(u & 0xffff0000u));
}

extern "C" void kernel_launch(void* const* d_in, const int* in_sizes, int n_in,
                              void* d_out, int out_size, void* d_ws, size_t ws_size,
                              hipStream_t stream) {
  const float* x     = (const float*)d_in[0];
  const int*   erows = (const int*)d_in[1];
  const int*   ecols = (const int*)d_in[2];
  const float* evals = (const float*)d_in[3];
  const float* w     = (const float*)d_in[4];
  const float* bias  = (const float*)d_in[5];
  float* out = (float*)d_out;

  const int n_nodes = in_sizes[0] / 256;
  const int n_edges = in_sizes[1];
  const int nb_buckets = (n_nodes + BROWS - 1) >> BSHIFT;

  // ws carve-up (256B aligned so bcv regions are line-aligned)
  char* ws = (char*)d_ws;
  size_t off = 0;
  ushort* h  = (ushort*)(ws + off);  off += ((size_t)n_nodes * 128 * 2 + 255) & ~255ull;
  ushort* wt = (ushort*)(ws + off);  off += ((size_t)128 * WT_K * 2 + 255) & ~255ull;
  const size_t cur_ints = (((size_t)nb_buckets) << CSH) + 16;  // + ovf_cnt slot
  int* cursors = (int*)(ws + off);   off += (cur_ints * 4 + 255) & ~255ull;
  int2* bcv    = (int2*)(ws + off);  off += ((size_t)nb_buckets * CAP * 8 + 255) & ~255ull;
  int4* ovf    = (int4*)(ws + off);  off += (size_t)OVFCAP * 16;
  const bool bucket_ok = (off <= ws_size) && (nb_buckets <= NBMAX) &&
                         (n_nodes <= 102400);
  int* ovf_cnt = cursors + (((size_t)nb_buckets) << CSH);

  const int zero_ints = bucket_ok ? (int)cur_ints : 0;
  conv_w<<<128, 256, 0, stream>>>(w, wt, cursors, zero_ints);
  const int gemm_blocks = (n_nodes + GM_NODES - 1) / GM_NODES;
  gemm_mfma<<<gemm_blocks, 256, 0, stream>>>(x, wt, h, n_nodes);

  if (bucket_ok) {
    const int eblocks = (n_edges + EPB - 1) / EPB;
    fill_bin<<<eblocks, 256, 0, stream>>>(erows, ecols, evals, cursors, bcv,
                                          ovf_cnt, ovf, n_edges, nb_buckets);
    sort_gather<<<nb_buckets, 256, 0, stream>>>(h, cursors, bcv, bias, out,
                                                n_nodes, nb_buckets);
    ovf_scatter<<<32, 256, 0, stream>>>(h, ovf_cnt, ovf, out);
  } else {
    const int n4 = out_size / 4;
    init_bias<<<(n4 + 255) / 256, 256, 0, stream>>>(out, bias, n4);
    scatter_edges<<<(n_edges + 3) / 4, 256, 0, stream>>>(h, erows, ecols, evals,
                                                         out, n_edges);
  }
}

// Round 9
// 293.212 us; speedup vs baseline: 1.0350x; 1.0350x over previous
//
#include <hip/hip_runtime.h>

// GCNConv forward: out = segment_sum(vals * (x@W)[cols], rows) + bias
// Round 16:
//  - FUSE gemm + fill_bin into one dispatch (they are independent; the
//    stream serialized them). Role-partitioned blocks, interleaved so each
//    CU co-schedules a BW-bound gemm block with a latency-bound fill block
//    (complementary pipes). LDS union 67.6KB -> 2 blocks/CU both roles
//    (fill EPB 6400->4800 to fit under gemm's lw).
//  - sort_gather reverted to r14 register-sort (r15 half-wave pairing was
//    +4us / VALU+10%: gather floor ~67us is fabric-latency, not MLP).
//
// ws: h[N*128] bf16 | wt[128*264] bf16 | cursors[(NB<<4)+16] int |
//     bcv[NB*CAP] int2 | ovf[OVFCAP] int4

typedef __attribute__((ext_vector_type(8))) short short8;
typedef __attribute__((ext_vector_type(4))) float floatx4;
typedef __attribute__((ext_vector_type(2))) int intv2;

#define WT_K 264
#define GM_NODES 128
#define BSHIFT 6              // 64 rows per bucket
#define BROWS 64
#define CAP 1280              // records per bucket region; mean 1024, +8 sigma
#define NBMAX 1600            // max buckets (n_nodes <= 102400)
#define EPB 4800              // edges per fill block (LDS union fit)
#define CSH 4                 // cursors padded to 16 ints = one 64B line
#define OVFCAP 65536
#define SMEM_BYTES 67584      // max(gemm 67584, fill 67200)

static __device__ __forceinline__ uint f2bf(float x) {  // RNE f32->bf16 bits
  uint u = __float_as_uint(x);
  return (u + 0x7fffu + ((u >> 16) & 1u)) >> 16;
}

union u4s8 { uint4 u; short8 s; };

// ---- W[k][f] f32 -> wt[f][k] bf16 (k padded to WT_K); also zero cursors ----
__global__ __launch_bounds__(256) void conv_w(const float* __restrict__ w,
                                              ushort* __restrict__ wt,
                                              int* __restrict__ cursors,
                                              int n_ints) {
  const int f = blockIdx.x;
  const int k = threadIdx.x;
  wt[f * WT_K + k] = (ushort)f2bf(w[k * 128 + f]);
  for (int i = blockIdx.x * 256 + threadIdx.x; i < n_ints; i += 128 * 256)
    cursors[i] = 0;
}

// ---- gemm block body: 128 nodes, barrier-free k-loop, W in LDS ----
static __device__ __forceinline__ void gemm_body(
    const float* __restrict__ x, const ushort* __restrict__ wt,
    ushort* __restrict__ h, int n_nodes, int row0, char* smem) {
  ushort* lw = (ushort*)smem;
  const int t = threadIdx.x;
  const int lane = t & 63;
  const int wq = t >> 6;
  const int quad = lane >> 4;
  const int l15 = lane & 15;

  {
    const uint4* src = (const uint4*)wt;
    uint4* dst = (uint4*)lw;
    for (int i = t; i < (128 * WT_K * 2) / 16; i += 256) dst[i] = src[i];
  }

  floatx4 acc[2][8];
#pragma unroll
  for (int nt = 0; nt < 2; ++nt)
#pragma unroll
    for (int mt = 0; mt < 8; ++mt) acc[nt][mt] = (floatx4){0.f, 0.f, 0.f, 0.f};

  const int n0 = row0 + wq * 32 + l15;
  const int n1 = n0 + 16;
  const bool v0 = (n0 < n_nodes), v1 = (n1 < n_nodes);
  const float* p0 = x + (size_t)(v0 ? n0 : 0) * 256 + quad * 8;
  const float* p1 = x + (size_t)(v1 ? n1 : 0) * 256 + quad * 8;
  const float4 z4 = make_float4(0.f, 0.f, 0.f, 0.f);

  float4 cur0a = v0 ? *(const float4*)(p0 + 0) : z4;
  float4 cur0b = v0 ? *(const float4*)(p0 + 4) : z4;
  float4 cur1a = v1 ? *(const float4*)(p1 + 0) : z4;
  float4 cur1b = v1 ? *(const float4*)(p1 + 4) : z4;

  __syncthreads();   // W staged

  for (int kc = 0; kc < 8; ++kc) {
    float4 nxt0a, nxt0b, nxt1a, nxt1b;
    if (kc < 7) {
      const int o = (kc + 1) * 32;
      nxt0a = v0 ? *(const float4*)(p0 + o + 0) : z4;
      nxt0b = v0 ? *(const float4*)(p0 + o + 4) : z4;
      nxt1a = v1 ? *(const float4*)(p1 + o + 0) : z4;
      nxt1b = v1 ? *(const float4*)(p1 + o + 4) : z4;
    }

    u4s8 bf0, bf1;
    bf0.u.x = f2bf(cur0a.x) | (f2bf(cur0a.y) << 16);
    bf0.u.y = f2bf(cur0a.z) | (f2bf(cur0a.w) << 16);
    bf0.u.z = f2bf(cur0b.x) | (f2bf(cur0b.y) << 16);
    bf0.u.w = f2bf(cur0b.z) | (f2bf(cur0b.w) << 16);
    bf1.u.x = f2bf(cur1a.x) | (f2bf(cur1a.y) << 16);
    bf1.u.y = f2bf(cur1a.z) | (f2bf(cur1a.w) << 16);
    bf1.u.z = f2bf(cur1b.x) | (f2bf(cur1b.y) << 16);
    bf1.u.w = f2bf(cur1b.z) | (f2bf(cur1b.w) << 16);

#pragma unroll
    for (int mt = 0; mt < 8; ++mt) {
      const short8 afr =
          *(const short8*)&lw[(mt * 16 + l15) * WT_K + kc * 32 + quad * 8];
      acc[0][mt] = __builtin_amdgcn_mfma_f32_16x16x32_bf16(afr, bf0.s,
                                                           acc[0][mt], 0, 0, 0);
      acc[1][mt] = __builtin_amdgcn_mfma_f32_16x16x32_bf16(afr, bf1.s,
                                                           acc[1][mt], 0, 0, 0);
    }
    cur0a = nxt0a; cur0b = nxt0b; cur1a = nxt1a; cur1b = nxt1b;
  }

#pragma unroll
  for (int nt = 0; nt < 2; ++nt) {
    const int node = row0 + wq * 32 + nt * 16 + l15;
    if (node < n_nodes) {
#pragma unroll
      for (int mt = 0; mt < 8; ++mt) {
        uint2 p;
        p.x = f2bf(acc[nt][mt][0]) | (f2bf(acc[nt][mt][1]) << 16);
        p.y = f2bf(acc[nt][mt][2]) | (f2bf(acc[nt][mt][3]) << 16);
        *(uint2*)&h[(size_t)node * 128 + mt * 16 + quad * 4] = p;
      }
    }
  }
}

// ---- fill block body: EPB edges, LDS histogram + 1 atomic/(block,bucket) ----
static __device__ __forceinline__ void fill_body(
    const int* __restrict__ erows, const int* __restrict__ ecols,
    const float* __restrict__ evals, int* __restrict__ cursors,
    int2* __restrict__ bcv, int* __restrict__ ovf_cnt,
    int4* __restrict__ ovf, int n_edges, int nb, int e0, char* smem) {
  int2* rec = (int2*)smem;                       // EPB*8   = 38400
  short* bkt = (short*)(smem + EPB * 8);         // EPB*2   =  9600
  int* cnt = (int*)(smem + EPB * 10);            // NBMAX*4 =  6400
  int* bas = cnt + NBMAX;
  int* cur = bas + NBMAX;
  const int t = threadIdx.x;
  const int n = min(EPB, n_edges - e0);
  if (n <= 0) return;

  for (int b = t; b < nb; b += 256) { cnt[b] = 0; cur[b] = 0; }
  __syncthreads();

  // load + pack + LDS histogram (coalesced NT sweep, 4-batched for MLP)
  {
    int i = t;
    for (; i + 768 < n; i += 1024) {
      int r0 = __builtin_nontemporal_load(&erows[e0 + i]);
      int r1 = __builtin_nontemporal_load(&erows[e0 + i + 256]);
      int r2 = __builtin_nontemporal_load(&erows[e0 + i + 512]);
      int r3 = __builtin_nontemporal_load(&erows[e0 + i + 768]);
      int c0 = __builtin_nontemporal_load(&ecols[e0 + i]);
      int c1 = __builtin_nontemporal_load(&ecols[e0 + i + 256]);
      int c2 = __builtin_nontemporal_load(&ecols[e0 + i + 512]);
      int c3 = __builtin_nontemporal_load(&ecols[e0 + i + 768]);
      float v0 = __builtin_nontemporal_load(&evals[e0 + i]);
      float v1 = __builtin_nontemporal_load(&evals[e0 + i + 256]);
      float v2 = __builtin_nontemporal_load(&evals[e0 + i + 512]);
      float v3 = __builtin_nontemporal_load(&evals[e0 + i + 768]);
      int2 p0; p0.x = c0 | ((r0 & (BROWS - 1)) << 17); p0.y = __float_as_int(v0);
      int2 p1; p1.x = c1 | ((r1 & (BROWS - 1)) << 17); p1.y = __float_as_int(v1);
      int2 p2; p2.x = c2 | ((r2 & (BROWS - 1)) << 17); p2.y = __float_as_int(v2);
      int2 p3; p3.x = c3 | ((r3 & (BROWS - 1)) << 17); p3.y = __float_as_int(v3);
      rec[i] = p0; rec[i + 256] = p1; rec[i + 512] = p2; rec[i + 768] = p3;
      const int b0 = r0 >> BSHIFT, b1 = r1 >> BSHIFT;
      const int b2 = r2 >> BSHIFT, b3 = r3 >> BSHIFT;
      bkt[i] = (short)b0; bkt[i + 256] = (short)b1;
      bkt[i + 512] = (short)b2; bkt[i + 768] = (short)b3;
      atomicAdd(&cnt[b0], 1); atomicAdd(&cnt[b1], 1);
      atomicAdd(&cnt[b2], 1); atomicAdd(&cnt[b3], 1);
    }
    for (; i < n; i += 256) {
      const int r = __builtin_nontemporal_load(&erows[e0 + i]);
      const int c = __builtin_nontemporal_load(&ecols[e0 + i]);
      const float v = __builtin_nontemporal_load(&evals[e0 + i]);
      int2 p; p.x = c | ((r & (BROWS - 1)) << 17); p.y = __float_as_int(v);
      rec[i] = p;
      const int b = r >> BSHIFT;
      bkt[i] = (short)b;
      atomicAdd(&cnt[b], 1);
    }
  }
  __syncthreads();

  // reserve global runs: one atomic per non-empty (block,bucket); 256-wide
  for (int b = t; b < nb; b += 256) {
    const int c = cnt[b];
    if (c > 0) bas[b] = atomicAdd(&cursors[b << CSH], c);
  }
  __syncthreads();

  // flush: contiguous 8B-record runs per bucket
  for (int i = t; i < n; i += 256) {
    const int b = (int)bkt[i];
    const int loc = atomicAdd(&cur[b], 1);
    const int pos = bas[b] + loc;
    const int2 p = rec[i];
    if (pos < CAP) {
      bcv[(size_t)b * CAP + pos] = p;
    } else {
      int op = atomicAdd(ovf_cnt, 1);
      if (op < OVFCAP) {
        int4 q;
        q.x = (b << BSHIFT) | ((p.x >> 17) & (BROWS - 1));   // row
        q.y = p.x & 0x1FFFF;                                 // col
        q.z = p.y; q.w = 0;
        ovf[op] = q;
      }
    }
  }
}

// ---- fused dispatch: interleaved gemm-role / fill-role blocks ----
__global__ __launch_bounds__(256) void gemm_fill(
    const float* __restrict__ x, const ushort* __restrict__ wt,
    ushort* __restrict__ h, const int* __restrict__ erows,
    const int* __restrict__ ecols, const float* __restrict__ evals,
    int* __restrict__ cursors, int2* __restrict__ bcv,
    int* __restrict__ ovf_cnt, int4* __restrict__ ovf,
    int n_nodes, int n_edges, int nb, int nfill) {
  __shared__ __align__(16) char smem[SMEM_BYTES];
  const int bid = blockIdx.x;
  const int total = gridDim.x;
  const int nf2 = nfill * 2;
  int role, rid;
  if (nf2 <= total) {
    if (bid < nf2) { role = bid & 1; rid = bid >> 1; }
    else           { role = 0;       rid = bid - nfill; }
  } else {
    role = (bid < nfill) ? 1 : 0;
    rid = role ? bid : bid - nfill;
  }
  if (role == 0) {
    gemm_body(x, wt, h, n_nodes, rid * GM_NODES, smem);
  } else {
    fill_body(erows, ecols, evals, cursors, bcv, ovf_cnt, ovf, n_edges, nb,
              rid * EPB, smem);
  }
}

// ---- standalone gemm (fallback path) ----
__global__ __launch_bounds__(256) void gemm_mfma(const float* __restrict__ x,
                                                 const ushort* __restrict__ wt,
                                                 ushort* __restrict__ h,
                                                 int n_nodes) {
  __shared__ __align__(16) char smem[SMEM_BYTES];
  gemm_body(x, wt, h, n_nodes, blockIdx.x * GM_NODES, smem);
}

// ---- fused per-bucket counting sort (regs->LDS) + node gather (r14) ----
__global__ __launch_bounds__(256) void sort_gather(
    const ushort* __restrict__ h, const int* __restrict__ cursors,
    const int2* __restrict__ bcv, const float* __restrict__ bias,
    float* __restrict__ out, int n_nodes, int nb) {
  __shared__ int2 buf[CAP];            // 10.24 KB sorted records
  __shared__ int cnt[BROWS], start[BROWS], cur[BROWS];
  const int b = blockIdx.x;
  const int t = threadIdx.x;
  const int nrec = min(cursors[b << CSH], CAP);
  if (t < BROWS) cnt[t] = 0;
  __syncthreads();

  const int2* src = &bcv[(size_t)b * CAP];
  int2 r[5];
#pragma unroll
  for (int j = 0; j < 5; ++j) {
    const int i = t + j * 256;
    if (i < nrec) {
      intv2 rv = __builtin_nontemporal_load((const intv2*)&src[i]);
      r[j].x = rv[0]; r[j].y = rv[1];
    } else {
      r[j].x = 0; r[j].y = 0;
    }
  }
#pragma unroll
  for (int j = 0; j < 5; ++j) {
    const int i = t + j * 256;
    if (i < nrec) atomicAdd(&cnt[((uint)r[j].x) >> 17], 1);
  }
  __syncthreads();

  if (t < BROWS) {   // wave 0: 64-lane inclusive scan -> exclusive starts
    int c = cnt[t];
    int s = c;
#pragma unroll
    for (int off = 1; off < 64; off <<= 1) {
      int u = __shfl_up(s, off, 64);
      if (t >= off) s += u;
    }
    start[t] = s - c;
    cur[t] = s - c;
  }
  __syncthreads();

  // scatter into row-sorted LDS buffer (from regs; single global pass)
#pragma unroll
  for (int j = 0; j < 5; ++j) {
    const int i = t + j * 256;
    if (i < nrec) {
      int pos = atomicAdd(&cur[((uint)r[j].x) >> 17], 1);
      buf[pos] = r[j];
    }
  }
  __syncthreads();

  // gather: wave w handles rows w*16 .. w*16+15; 8-deep MLP, dual acc chains
  const int lane = t & 63;
  const int w = t >> 6;
  const float2 bv = ((const float2*)bias)[lane];
  for (int rr = w * 16; rr < w * 16 + 16; ++rr) {
    const int node = b * BROWS + rr;
    if (node >= n_nodes) break;
    float2 acca = bv;
    float2 accb = make_float2(0.f, 0.f);
    int p = start[rr];
    const int p1 = start[rr] + cnt[rr];
    for (; p + 8 <= p1; p += 8) {
      int2 e0 = buf[p + 0];
      int2 e1 = buf[p + 1];
      int2 e2 = buf[p + 2];
      int2 e3 = buf[p + 3];
      int2 e4 = buf[p + 4];
      int2 e5 = buf[p + 5];
      int2 e6 = buf[p + 6];
      int2 e7 = buf[p + 7];
      uint u0 = ((const uint*)(h + (size_t)(e0.x & 0x1FFFF) * 128))[lane];
      uint u1 = ((const uint*)(h + (size_t)(e1.x & 0x1FFFF) * 128))[lane];
      uint u2 = ((const uint*)(h + (size_t)(e2.x & 0x1FFFF) * 128))[lane];
      uint u3 = ((const uint*)(h + (size_t)(e3.x & 0x1FFFF) * 128))[lane];
      uint u4 = ((const uint*)(h + (size_t)(e4.x & 0x1FFFF) * 128))[lane];
      uint u5 = ((const uint*)(h + (size_t)(e5.x & 0x1FFFF) * 128))[lane];
      uint u6 = ((const uint*)(h + (size_t)(e6.x & 0x1FFFF) * 128))[lane];
      uint u7 = ((const uint*)(h + (size_t)(e7.x & 0x1FFFF) * 128))[lane];
      float v0 = __int_as_float(e0.y), v1 = __int_as_float(e1.y);
      float v2 = __int_as_float(e2.y), v3 = __int_as_float(e3.y);
      float v4 = __int_as_float(e4.y), v5 = __int_as_float(e5.y);
      float v6 = __int_as_float(e6.y), v7 = __int_as_float(e7.y);
      acca.x += v0 * __uint_as_float(u0 << 16);
      acca.y += v0 * __uint_as_float(u0 & 0xffff0000u);
      accb.x += v1 * __uint_as_float(u1 << 16);
      accb.y += v1 * __uint_as_float(u1 & 0xffff0000u);
      acca.x += v2 * __uint_as_float(u2 << 16);
      acca.y += v2 * __uint_as_float(u2 & 0xffff0000u);
      accb.x += v3 * __uint_as_float(u3 << 16);
      accb.y += v3 * __uint_as_float(u3 & 0xffff0000u);
      acca.x += v4 * __uint_as_float(u4 << 16);
      acca.y += v4 * __uint_as_float(u4 & 0xffff0000u);
      accb.x += v5 * __uint_as_float(u5 << 16);
      accb.y += v5 * __uint_as_float(u5 & 0xffff0000u);
      acca.x += v6 * __uint_as_float(u6 << 16);
      acca.y += v6 * __uint_as_float(u6 & 0xffff0000u);
      accb.x += v7 * __uint_as_float(u7 << 16);
      accb.y += v7 * __uint_as_float(u7 & 0xffff0000u);
    }
    for (; p < p1; ++p) {
      int2 ev = buf[p];
      float v = __int_as_float(ev.y);
      uint u = ((const uint*)(h + (size_t)(ev.x & 0x1FFFF) * 128))[lane];
      acca.x += v * __uint_as_float(u << 16);
      acca.y += v * __uint_as_float(u & 0xffff0000u);
    }
    float2 accf;
    accf.x = acca.x + accb.x;
    accf.y = acca.y + accb.y;
    ((float2*)(out + (size_t)node * 128))[lane] = accf;
  }
}

// ---- drain overflow spill list (expected near-empty; fixed grid for graph) ----
__global__ __launch_bounds__(256) void ovf_scatter(
    const ushort* __restrict__ h, const int* __restrict__ ovf_cnt,
    const int4* __restrict__ ovf, float* __restrict__ out) {
  const int n = min(*ovf_cnt, OVFCAP);
  const int lane = threadIdx.x & 63;
  const int wid = (blockIdx.x * 256 + threadIdx.x) >> 6;
  const int nw = gridDim.x * 4;
  for (int e = wid; e < n; e += nw) {
    int4 recq = ovf[e];
    float v = __int_as_float(recq.z);
    uint u = ((const uint*)(h + (size_t)recq.y * 128))[lane];
    float* op = out + (size_t)recq.x * 128 + lane * 2;
    atomicAdd(op, v * __uint_as_float(u << 16));
    atomicAdd(op + 1, v * __uint_as_float(u & 0xffff0000u));
  }
}

// ---- fallback (small ws): bias init + atomic scatter on bf16 h ----
__global__ __launch_bounds__(256) void init_bias(float* __restrict__ out,
                                                 const float* __restrict__ bias,
                                                 int n4) {
  int i = blockIdx.x * 256 + threadIdx.x;
  if (i < n4) {
    float4 b = ((const float4*)bias)[i & 31];
    ((float4*)out)[i] = b;
  }
}

__global__ __launch_bounds__(256) void scatter_edges(
    const ushort* __restrict__ h, const int* __restrict__ erows,
    const int* __restrict__ ecols, const float* __restrict__ evals,
    float* __restrict__ out, int n_edges) {
  int e = blockIdx.x * 4 + (threadIdx.x >> 6);
  if (e >= n_edges) return;
  int lane = threadIdx.x & 63;
  int row = erows[e];
  int col = ecols[e];
  float v = evals[e];
  uint u = ((const uint*)(h + (size_t)col * 128))[lane];
  float* op = out + (size_t)row * 128 + lane * 2;
  atomicAdd(op, v * __uint_as_float(u << 16));
  atomicAdd(op + 1, v * __uint_as_float(u & 0xffff0000u));
}

extern "C" void kernel_launch(void* const* d_in, const int* in_sizes, int n_in,
                              void* d_out, int out_size, void* d_ws, size_t ws_size,
                              hipStream_t stream) {
  const float* x     = (const float*)d_in[0];
  const int*   erows = (const int*)d_in[1];
  const int*   ecols = (const int*)d_in[2];
  const float* evals = (const float*)d_in[3];
  const float* w     = (const float*)d_in[4];
  const float* bias  = (const float*)d_in[5];
  float* out = (float*)d_out;

  const int n_nodes = in_sizes[0] / 256;
  const int n_edges = in_sizes[1];
  const int nb_buckets = (n_nodes + BROWS - 1) >> BSHIFT;

  // ws carve-up (256B aligned so bcv regions are line-aligned)
  char* ws = (char*)d_ws;
  size_t off = 0;
  ushort* h  = (ushort*)(ws + off);  off += ((size_t)n_nodes * 128 * 2 + 255) & ~255ull;
  ushort* wt = (ushort*)(ws + off);  off += ((size_t)128 * WT_K * 2 + 255) & ~255ull;
  const size_t cur_ints = (((size_t)nb_buckets) << CSH) + 16;  // + ovf_cnt slot
  int* cursors = (int*)(ws + off);   off += (cur_ints * 4 + 255) & ~255ull;
  int2* bcv    = (int2*)(ws + off);  off += ((size_t)nb_buckets * CAP * 8 + 255) & ~255ull;
  int4* ovf    = (int4*)(ws + off);  off += (size_t)OVFCAP * 16;
  const bool bucket_ok = (off <= ws_size) && (nb_buckets <= NBMAX) &&
                         (n_nodes <= 102400);
  int* ovf_cnt = cursors + (((size_t)nb_buckets) << CSH);

  const int zero_ints = bucket_ok ? (int)cur_ints : 0;
  conv_w<<<128, 256, 0, stream>>>(w, wt, cursors, zero_ints);

  if (bucket_ok) {
    const int ngemm = (n_nodes + GM_NODES - 1) / GM_NODES;
    const int nfill = (n_edges + EPB - 1) / EPB;
    gemm_fill<<<ngemm + nfill, 256, 0, stream>>>(
        x, wt, h, erows, ecols, evals, cursors, bcv, ovf_cnt, ovf,
        n_nodes, n_edges, nb_buckets, nfill);
    sort_gather<<<nb_buckets, 256, 0, stream>>>(h, cursors, bcv, bias, out,
                                                n_nodes, nb_buckets);
    ovf_scatter<<<32, 256, 0, stream>>>(h, ovf_cnt, ovf, out);
  } else {
    const int gemm_blocks = (n_nodes + GM_NODES - 1) / GM_NODES;
    gemm_mfma<<<gemm_blocks, 256, 0, stream>>>(x, wt, h, n_nodes);
    const int n4 = out_size / 4;
    init_bias<<<(n4 + 255) / 256, 256, 0, stream>>>(out, bias, n4);
    scatter_edges<<<(n_edges + 3) / 4, 256, 0, stream>>>(h, erows, ecols, evals,
                                                         out, n_edges);
  }
}